// Round 16
// baseline (249.503 us; speedup 1.0000x reference)
//
#include <hip/hip_runtime.h>
#include <math.h>

#define F_IN 32
#define NH 8
#define C1 8
#define D1 64
#define NEG 0.2f
#define LOG2E 1.44269504088896f
#define SHBIAS (-20.0f * LOG2E)   // fixed softmax shift (shift-invariant, avoids overflow)

typedef int iv4 __attribute__((ext_vector_type(4)));
typedef float fv2 __attribute__((ext_vector_type(2)));
typedef unsigned short ushort_t;

__device__ __forceinline__ ushort_t f2bf(float f) {   // RNE float->bf16
    unsigned int b = __float_as_uint(f);
    return (ushort_t)((b + 0x7FFF + ((b >> 16) & 1)) >> 16);
}

// =============== CSR build: two-level counting sort, ZERO global atomics ===============
// (R10-R12: ANY per-edge global atomic caps at ~22G/s = 143us on the memory-side
//  coherence point, regardless of layout. So: LDS atomics only.)

// ---- node1: h = x@W1 (stored bf16), attention logits a_s/a_d (f32) ----
__device__ __forceinline__ void node1_body(const float* __restrict__ x, const float* __restrict__ W1,
                                           const float* __restrict__ as1, const float* __restrict__ ad1,
                                           ushort_t* __restrict__ h1b, float* __restrict__ a_s,
                                           float* __restrict__ a_d, int N, int b) {
    __shared__ float sW[F_IN * D1];
    __shared__ float sA[2 * D1];
    for (int i = threadIdx.x; i < F_IN * D1; i += blockDim.x) sW[i] = W1[i];
    if (threadIdx.x < 2 * D1)
        sA[threadIdx.x] = (threadIdx.x < D1) ? as1[threadIdx.x] : ad1[threadIdx.x - D1];
    __syncthreads();
    int t = b * blockDim.x + threadIdx.x;
    int n = t >> 3, h = t & 7;
    if (n >= N) return;
    float xr[F_IN];
    const float4* xv = (const float4*)(x + n * F_IN);
#pragma unroll
    for (int k = 0; k < F_IN / 4; ++k) {
        float4 v = xv[k];
        xr[4 * k] = v.x; xr[4 * k + 1] = v.y; xr[4 * k + 2] = v.z; xr[4 * k + 3] = v.w;
    }
    float acc[C1];
#pragma unroll
    for (int c = 0; c < C1; ++c) acc[c] = 0.0f;
#pragma unroll
    for (int k = 0; k < F_IN; ++k) {
        float xk = xr[k];
#pragma unroll
        for (int c = 0; c < C1; ++c) acc[c] = fmaf(xk, sW[k * D1 + h * C1 + c], acc[c]);
    }
    float s_ = 0.0f, d_ = 0.0f;
    unsigned int w[4];
#pragma unroll
    for (int c = 0; c < C1; ++c) {
        s_ = fmaf(acc[c], sA[h * C1 + c], s_);
        d_ = fmaf(acc[c], sA[D1 + h * C1 + c], d_);
    }
#pragma unroll
    for (int k = 0; k < 4; ++k)
        w[k] = (unsigned int)f2bf(acc[2 * k]) | ((unsigned int)f2bf(acc[2 * k + 1]) << 16);
    iv4 wv = {(int)w[0], (int)w[1], (int)w[2], (int)w[3]};
    *(iv4*)(h1b + (size_t)n * D1 + h * C1) = wv;
    a_s[n * NH + h] = s_;
    a_d[n * NH + h] = d_;
}

// ---- Pass A (|| node1): per-block bucket histogram, 8192 edges/block ----
__global__ void __launch_bounds__(256)
k_bhist_node1(const int* __restrict__ ei, int E4, int GA, int nbk,
              int* __restrict__ blkcnt,
              const float* __restrict__ x, const float* __restrict__ W1,
              const float* __restrict__ as1, const float* __restrict__ ad1,
              ushort_t* __restrict__ h1b, float* __restrict__ a_s, float* __restrict__ a_d,
              int N) {
    int g = blockIdx.x;
    if (g >= GA) { node1_body(x, W1, as1, ad1, h1b, a_s, a_d, N, g - GA); return; }
    __shared__ int hist[512];
    for (int i = threadIdx.x; i < nbk; i += 256) hist[i] = 0;
    __syncthreads();
    const iv4* d4 = (const iv4*)ei + E4;
    int base = g * 2048 + threadIdx.x;
#pragma unroll
    for (int k = 0; k < 8; ++k) {
        int idx = base + k * 256;
        if (idx < E4) {
            iv4 d = __builtin_nontemporal_load(d4 + idx);
            atomicAdd(&hist[d.x >> 8], 1);
            atomicAdd(&hist[d.y >> 8], 1);
            atomicAdd(&hist[d.z >> 8], 1);
            atomicAdd(&hist[d.w >> 8], 1);
        }
    }
    __syncthreads();
    for (int i = threadIdx.x; i < nbk; i += 256) blkcnt[(size_t)i * GA + g] = hist[i];
}

// ---- Pass B: two-level exclusive scan over flat blkcnt (F = nbk*GA) ----
__global__ void k_scan_block(const int* __restrict__ in, int* __restrict__ tmp,
                             int* __restrict__ bsum, int F) {
    __shared__ int s[256];
    int i = blockIdx.x * 256 + threadIdx.x;
    int v = (i < F) ? in[i] : 0;
    s[threadIdx.x] = v;
    __syncthreads();
#pragma unroll
    for (int off = 1; off < 256; off <<= 1) {
        int t = (threadIdx.x >= off) ? s[threadIdx.x - off] : 0;
        __syncthreads();
        s[threadIdx.x] += t;
        __syncthreads();
    }
    tmp[i] = s[threadIdx.x] - v;
    if (threadIdx.x == 255) bsum[blockIdx.x] = s[255];
}

__global__ void k_scan_bsums1024(int* __restrict__ bsum, int nb) {
    __shared__ int s[1024];
    int t = threadIdx.x;
    s[t] = (t < nb) ? bsum[t] : 0;
    __syncthreads();
#pragma unroll
    for (int off = 1; off < 1024; off <<= 1) {
        int v = (t >= off) ? s[t - off] : 0;
        __syncthreads();
        s[t] += v;
        __syncthreads();
    }
    if (t < nb) bsum[t] = (t == 0) ? 0 : s[t - 1];
}

__global__ void k_scan_fin(const int* __restrict__ tmp, const int* __restrict__ bsum,
                           int* __restrict__ excl, int F, int E) {
    int i = blockIdx.x * blockDim.x + threadIdx.x;
    if (i > F) return;
    excl[i] = (i < F) ? (tmp[i] + bsum[i >> 8]) : E;
}

// ---- Pass C: partition edges into bucket windows (LDS cursors, nt stores) ----
__global__ void __launch_bounds__(256)
k_part(const int* __restrict__ ei, int E4, int GA, int nbk,
       const int* __restrict__ excl, int* __restrict__ partbuf) {
    __shared__ int cur[512];
    int g = blockIdx.x;
    for (int i = threadIdx.x; i < nbk; i += 256) cur[i] = excl[(size_t)i * GA + g];
    __syncthreads();
    const iv4* s4 = (const iv4*)ei;
    const iv4* d4 = s4 + E4;
    int base = g * 2048 + threadIdx.x;
#pragma unroll
    for (int k = 0; k < 8; ++k) {
        int idx = base + k * 256;
        if (idx < E4) {
            iv4 d = __builtin_nontemporal_load(d4 + idx);
            iv4 s = __builtin_nontemporal_load(s4 + idx);
            int dd[4] = {d.x, d.y, d.z, d.w};
            int ss[4] = {s.x, s.y, s.z, s.w};
#pragma unroll
            for (int u = 0; u < 4; ++u) {
                int pos = atomicAdd(&cur[dd[u] >> 8], 1);
                __builtin_nontemporal_store((ss[u] << 8) | (dd[u] & 255), partbuf + pos);
            }
        }
    }
}

// ---- Pass D: per-bucket CSR (LDS node hist + scan; self-loop = slot 0) ----
__global__ void __launch_bounds__(256)
k_csr(const int* __restrict__ excl, const int* __restrict__ partbuf,
      int* __restrict__ ptr, int* __restrict__ srcs, int N, int GA, int nbk, int Et) {
    __shared__ int lcnt[256];
    __shared__ int lsc[256];
    int b = blockIdx.x;
    int tid = threadIdx.x;
    int pStart = excl[(size_t)b * GA];
    int pEnd   = excl[(size_t)(b + 1) * GA];   // b==nbk-1 -> excl[F] = E
    int node = (b << 8) + tid;
    int exists = (node < N) ? 1 : 0;
    lcnt[tid] = exists;                        // slot 0 reserved for self-loop
    __syncthreads();
    for (int i = pStart + tid; i < pEnd; i += 256)
        atomicAdd(&lcnt[partbuf[i] & 255], 1);
    __syncthreads();
    int v = lcnt[tid];
    lsc[tid] = v;
    __syncthreads();
#pragma unroll
    for (int off = 1; off < 256; off <<= 1) {
        int t = (tid >= off) ? lsc[tid - off] : 0;
        __syncthreads();
        lsc[tid] += t;
        __syncthreads();
    }
    int exclv = lsc[tid] - v;
    int finalBase = pStart + (b << 8);         // + self-loops of earlier buckets
    if (exists) {
        int p = finalBase + exclv;
        ptr[node] = p;
        srcs[p] = node;                        // self-loop at rank 0
    }
    if (b == nbk - 1 && tid == 0) ptr[N] = Et;
    __syncthreads();
    lcnt[tid] = exclv + exists;                // cursor: next free slot after self-loop
    __syncthreads();
    for (int i = pStart + tid; i < pEnd; i += 256) {
        int pv = partbuf[i];
        int r = atomicAdd(&lcnt[pv & 255], 1);
        srcs[finalBase + r] = pv >> 8;
    }
}

// ---------------- layer 1: wave per node, vectorized row gather ----------------
// Lane (j = l>>3, h = l&7). 32-edge maskless main (4 groups, 16 loads in flight),
// maskless 8-groups, then one masked group. Hi-channel unpack is FREE:
// __uint_as_float(dw) = hi bf16 value + lo bits as extra mantissa (rel err <2^-9,
// inside bf16 quantization). Lo-channel = dw<<16 exact.

__device__ __forceinline__ float lrelu(float e) { return e > 0.0f ? e : NEG * e; }

__device__ __forceinline__ void acc_group(const iv4& hv, float ex, fv2* acc2) {
    int dw[4] = {hv.x, hv.y, hv.z, hv.w};
    fv2 ev = {ex, ex};
#pragma unroll
    for (int k = 0; k < 4; ++k) {
        fv2 g = {__uint_as_float(((unsigned int)dw[k]) << 16),
                 __uint_as_float((unsigned int)dw[k])};
        acc2[k] += ev * g;
    }
}

__global__ void __launch_bounds__(256)
k_gat1(const int* __restrict__ ptr, const int* __restrict__ srcs,
       const float* __restrict__ a_s, const float* __restrict__ a_d,
       const ushort_t* __restrict__ h1b,
       const float* __restrict__ b1, const float* __restrict__ W2,
       const float* __restrict__ as2, const float* __restrict__ ad2,
       float4* __restrict__ p2, int N) {
    __shared__ float sB1[D1];
    __shared__ float sW2[D1 * 2];
    __shared__ float sA2[4];
    if (threadIdx.x < D1) sB1[threadIdx.x] = b1[threadIdx.x];
    else if (threadIdx.x < D1 * 3) sW2[threadIdx.x - D1] = W2[threadIdx.x - D1];
    else if (threadIdx.x < D1 * 3 + 2) sA2[threadIdx.x - D1 * 3] = as2[threadIdx.x - D1 * 3];
    else if (threadIdx.x < D1 * 3 + 4) sA2[threadIdx.x - D1 * 3] = ad2[threadIdx.x - D1 * 3 - 2];
    __syncthreads();
    int n = (blockIdx.x * blockDim.x + threadIdx.x) >> 6;
    if (n >= N) return;
    int l = threadIdx.x & 63;
    int j = l >> 3;          // edge slot
    int h = l & 7;           // head
    int start = ptr[n], end = ptr[n + 1];
    float ad = a_d[n * NH + h];
    float den = 0.0f;
    fv2 acc2[4];
#pragma unroll
    for (int k = 0; k < 4; ++k) acc2[k] = (fv2){0.0f, 0.0f};
    int base = start;
    // 32-edge maskless main: 4 groups, 12 independent gathers in flight
    for (; base + 32 <= end; base += 32) {
        int i0 = base + j;
        int s0 = srcs[i0], s1 = srcs[i0 + 8], s2 = srcs[i0 + 16], s3 = srcs[i0 + 24];
        float as0 = a_s[(s0 << 3) + h], as1 = a_s[(s1 << 3) + h];
        float as2_ = a_s[(s2 << 3) + h], as3 = a_s[(s3 << 3) + h];
        iv4 hv0 = *(const iv4*)(h1b + ((size_t)s0 << 6) + (h << 3));
        iv4 hv1 = *(const iv4*)(h1b + ((size_t)s1 << 6) + (h << 3));
        iv4 hv2 = *(const iv4*)(h1b + ((size_t)s2 << 6) + (h << 3));
        iv4 hv3 = *(const iv4*)(h1b + ((size_t)s3 << 6) + (h << 3));
        float ex0 = exp2f(fmaf(lrelu(as0 + ad), LOG2E, SHBIAS));
        float ex1 = exp2f(fmaf(lrelu(as1 + ad), LOG2E, SHBIAS));
        float ex2 = exp2f(fmaf(lrelu(as2_ + ad), LOG2E, SHBIAS));
        float ex3 = exp2f(fmaf(lrelu(as3 + ad), LOG2E, SHBIAS));
        den += (ex0 + ex1) + (ex2 + ex3);
        acc_group(hv0, ex0, acc2);
        acc_group(hv1, ex1, acc2);
        acc_group(hv2, ex2, acc2);
        acc_group(hv3, ex3, acc2);
    }
    // maskless 8-edge groups
    for (; base + 8 <= end; base += 8) {
        int s = srcs[base + j];
        float as = a_s[(s << 3) + h];
        iv4 hv = *(const iv4*)(h1b + ((size_t)s << 6) + (h << 3));
        float ex = exp2f(fmaf(lrelu(as + ad), LOG2E, SHBIAS));
        den += ex;
        acc_group(hv, ex, acc2);
    }
    // single masked group (<8 edges)
    if (base < end) {
        int idxl = base + j;
        bool valid = idxl < end;
        if (!valid) idxl = end - 1;
        int s = srcs[idxl];
        float as = a_s[(s << 3) + h];
        iv4 hv = *(const iv4*)(h1b + ((size_t)s << 6) + (h << 3));
        float ex = exp2f(fmaf(lrelu(as + ad), LOG2E, SHBIAS));
        if (!valid) ex = 0.0f;
        den += ex;
        acc_group(hv, ex, acc2);
    }
    // reduce over j (lane bits 3..5)
    den += __shfl_xor(den, 8, 64);
    den += __shfl_xor(den, 16, 64);
    den += __shfl_xor(den, 32, 64);
    float acc[8];
#pragma unroll
    for (int k = 0; k < 4; ++k) { acc[2 * k] = acc2[k].x; acc[2 * k + 1] = acc2[k].y; }
#pragma unroll
    for (int c = 0; c < 8; ++c) {
        acc[c] += __shfl_xor(acc[c], 8, 64);
        acc[c] += __shfl_xor(acc[c], 16, 64);
        acc[c] += __shfl_xor(acc[c], 32, 64);
    }
    float inv = 1.0f / den;
    float r0 = 0.0f, r1 = 0.0f;
#pragma unroll
    for (int c = 0; c < 8; ++c) {
        int col = (h << 3) + c;
        float v = fmaf(acc[c], inv, sB1[col]);
        v = v > 0.0f ? v : expm1f(v);    // ELU
        r0 = fmaf(v, sW2[col * 2 + 0], r0);
        r1 = fmaf(v, sW2[col * 2 + 1], r1);
    }
    // sum over h (lane bits 0..2)
    r0 += __shfl_xor(r0, 1, 64); r0 += __shfl_xor(r0, 2, 64); r0 += __shfl_xor(r0, 4, 64);
    r1 += __shfl_xor(r1, 1, 64); r1 += __shfl_xor(r1, 2, 64); r1 += __shfl_xor(r1, 4, 64);
    if (l == 0) {
        // packed node record for layer 2: (a_s2, a_d2, h2_0, h2_1)
        p2[n] = make_float4(r0 * sA2[0] + r1 * sA2[1],
                            r0 * sA2[2] + r1 * sA2[3], r0, r1);
    }
}

// ---------------- layer 2: 16 lanes per node, single 16B gather ----------------

__global__ void k_gat2(const int* __restrict__ ptr, const int* __restrict__ srcs,
                       const float4* __restrict__ p2, const float* __restrict__ b2,
                       float* __restrict__ out, int N) {
    int t = blockIdx.x * blockDim.x + threadIdx.x;
    int n = t >> 4;
    if (n >= N) return;
    int l = threadIdx.x & 15;
    int start = ptr[n], end = ptr[n + 1];
    float ad = p2[n].y;
    float den = 0.0f, a0 = 0.0f, a1 = 0.0f;
    for (int idx = start + l; idx < end; idx += 16) {
        int s = srcs[idx];
        float4 ps = p2[s];
        float ex = exp2f(fmaf(lrelu(ps.x + ad), LOG2E, SHBIAS));
        den += ex;
        a0 = fmaf(ex, ps.z, a0);
        a1 = fmaf(ex, ps.w, a1);
    }
#pragma unroll
    for (int off = 8; off; off >>= 1) {
        den += __shfl_xor(den, off, 16);
        a0  += __shfl_xor(a0, off, 16);
        a1  += __shfl_xor(a1, off, 16);
    }
    if (l == 0) {
        float inv = 1.0f / den;
        float o0 = a0 * inv + b2[0];
        float o1 = a1 * inv + b2[1];
        float mx = fmaxf(o0, o1);
        float lse = mx + logf(__expf(o0 - mx) + __expf(o1 - mx));
        out[n * 2 + 0] = o0 - lse;
        out[n * 2 + 1] = o1 - lse;
    }
}

extern "C" void kernel_launch(void* const* d_in, const int* in_sizes, int n_in,
                              void* d_out, int out_size, void* d_ws, size_t ws_size,
                              hipStream_t stream) {
    const float* x   = (const float*)d_in[0];
    const int*   ei  = (const int*)d_in[1];
    const float* W1  = (const float*)d_in[2];
    const float* as1 = (const float*)d_in[3];
    const float* ad1 = (const float*)d_in[4];
    const float* b1  = (const float*)d_in[5];
    const float* W2  = (const float*)d_in[6];
    const float* as2 = (const float*)d_in[7];
    const float* ad2 = (const float*)d_in[8];
    const float* b2  = (const float*)d_in[9];
    float* out = (float*)d_out;

    const int N  = in_sizes[0] / F_IN;   // 100000
    const int E  = in_sizes[1] / 2;      // 3200000
    const int E4 = E / 4;                // 800000
    const int Et = E + N;
    const int nbk = (N + 255) >> 8;      // 391 buckets
    const int GA  = (E4 + 2047) >> 11;   // 391 edge-chunk blocks (8192 edges each)
    const int F   = nbk * GA;            // 152881 flat scan size
    const int nbScan = (F + 255) >> 8;   // 598 (<=1024)

    char* p = (char*)d_ws;
    ushort_t* h1b = (ushort_t*)p; p += (size_t)N * D1 * 2;   // bf16 h1 (12.8MB, 16B aligned)
    float4* p2  = (float4*)p; p += (size_t)N * 16;           // packed layer-2 node record
    float* a_s1 = (float*)p; p += (size_t)N * NH * 4;
    float* a_d1 = (float*)p; p += (size_t)N * NH * 4;
    int* blkcnt = (int*)p;   p += (size_t)F * 4;
    int* tmp    = (int*)p;   p += (size_t)nbScan * 256 * 4;
    int* bsum   = (int*)p;   p += (size_t)nbScan * 4;
    int* excl   = (int*)p;   p += (size_t)(F + 1) * 4;
    int* partbuf= (int*)p;   p += (size_t)E * 4;
    int* ptr    = (int*)p;   p += (size_t)(N + 1) * 4;
    int* srcs   = (int*)p;   p += (size_t)Et * 4;

    const int nN1 = (N * NH + 255) / 256;    // 3125 node1 blocks

    hipLaunchKernelGGL(k_bhist_node1, dim3(GA + nN1), dim3(256), 0, stream,
                       ei, E4, GA, nbk, blkcnt, x, W1, as1, ad1, h1b, a_s1, a_d1, N);

    hipLaunchKernelGGL(k_scan_block, dim3(nbScan), dim3(256), 0, stream, blkcnt, tmp, bsum, F);
    hipLaunchKernelGGL(k_scan_bsums1024, dim3(1), dim3(1024), 0, stream, bsum, nbScan);
    hipLaunchKernelGGL(k_scan_fin, dim3((F + 256) / 256), dim3(256), 0, stream,
                       tmp, bsum, excl, F, E);

    hipLaunchKernelGGL(k_part, dim3(GA), dim3(256), 0, stream, ei, E4, GA, nbk, excl, partbuf);

    hipLaunchKernelGGL(k_csr, dim3(nbk), dim3(256), 0, stream,
                       excl, partbuf, ptr, srcs, N, GA, nbk, Et);

    hipLaunchKernelGGL(k_gat1, dim3((N + 3) / 4), dim3(256), 0, stream,
                       ptr, srcs, a_s1, a_d1, h1b, b1, W2, as2, ad2, p2, N);

    hipLaunchKernelGGL(k_gat2, dim3((N * 16 + 255) / 256), dim3(256), 0, stream,
                       ptr, srcs, p2, b2, out, N);
}

// Round 17
// 215.071 us; speedup vs baseline: 1.1601x; 1.1601x over previous
//
#include <hip/hip_runtime.h>
#include <math.h>

#define F_IN 32
#define NH 8
#define C1 8
#define D1 64
#define NEG 0.2f
#define LOG2E 1.44269504088896f
#define SHBIAS (-20.0f * LOG2E)   // fixed softmax shift (shift-invariant, avoids overflow)

typedef int iv4 __attribute__((ext_vector_type(4)));
typedef float fv2 __attribute__((ext_vector_type(2)));
typedef unsigned short ushort_t;

__device__ __forceinline__ ushort_t f2bf(float f) {   // RNE float->bf16
    unsigned int b = __float_as_uint(f);
    return (ushort_t)((b + 0x7FFF + ((b >> 16) & 1)) >> 16);
}

// =============== CSR build: two-level counting sort, ZERO global atomics ===============
// (R10-R12: ANY per-edge global atomic caps at ~22G/s = 143us on the memory-side
//  coherence point, regardless of layout. So: LDS atomics only.)

// ---- node1: h = x@W1 (stored bf16), dst attention logit a_d (f32) ----
// (a_s is NOT materialized: gat1 recomputes it from the gathered h1 row - R17)
__device__ __forceinline__ void node1_body(const float* __restrict__ x, const float* __restrict__ W1,
                                           const float* __restrict__ ad1,
                                           ushort_t* __restrict__ h1b,
                                           float* __restrict__ a_d, int N, int b) {
    __shared__ float sW[F_IN * D1];
    __shared__ float sA[D1];
    for (int i = threadIdx.x; i < F_IN * D1; i += blockDim.x) sW[i] = W1[i];
    if (threadIdx.x < D1) sA[threadIdx.x] = ad1[threadIdx.x];
    __syncthreads();
    int t = b * blockDim.x + threadIdx.x;
    int n = t >> 3, h = t & 7;
    if (n >= N) return;
    float xr[F_IN];
    const float4* xv = (const float4*)(x + n * F_IN);
#pragma unroll
    for (int k = 0; k < F_IN / 4; ++k) {
        float4 v = xv[k];
        xr[4 * k] = v.x; xr[4 * k + 1] = v.y; xr[4 * k + 2] = v.z; xr[4 * k + 3] = v.w;
    }
    float acc[C1];
#pragma unroll
    for (int c = 0; c < C1; ++c) acc[c] = 0.0f;
#pragma unroll
    for (int k = 0; k < F_IN; ++k) {
        float xk = xr[k];
#pragma unroll
        for (int c = 0; c < C1; ++c) acc[c] = fmaf(xk, sW[k * D1 + h * C1 + c], acc[c]);
    }
    float d_ = 0.0f;
    unsigned int w[4];
#pragma unroll
    for (int c = 0; c < C1; ++c) d_ = fmaf(acc[c], sA[h * C1 + c], d_);
#pragma unroll
    for (int k = 0; k < 4; ++k)
        w[k] = (unsigned int)f2bf(acc[2 * k]) | ((unsigned int)f2bf(acc[2 * k + 1]) << 16);
    iv4 wv = {(int)w[0], (int)w[1], (int)w[2], (int)w[3]};
    *(iv4*)(h1b + (size_t)n * D1 + h * C1) = wv;
    a_d[n * NH + h] = d_;
}

// ---- Pass A (|| node1): per-block bucket histogram, 8192 edges/block ----
__global__ void __launch_bounds__(256)
k_bhist_node1(const int* __restrict__ ei, int E4, int GA, int nbk,
              int* __restrict__ blkcnt,
              const float* __restrict__ x, const float* __restrict__ W1,
              const float* __restrict__ ad1,
              ushort_t* __restrict__ h1b, float* __restrict__ a_d,
              int N) {
    int g = blockIdx.x;
    if (g >= GA) { node1_body(x, W1, ad1, h1b, a_d, N, g - GA); return; }
    __shared__ int hist[512];
    for (int i = threadIdx.x; i < nbk; i += 256) hist[i] = 0;
    __syncthreads();
    const iv4* d4 = (const iv4*)ei + E4;
    int base = g * 2048 + threadIdx.x;
#pragma unroll
    for (int k = 0; k < 8; ++k) {
        int idx = base + k * 256;
        if (idx < E4) {
            iv4 d = __builtin_nontemporal_load(d4 + idx);
            atomicAdd(&hist[d.x >> 8], 1);
            atomicAdd(&hist[d.y >> 8], 1);
            atomicAdd(&hist[d.z >> 8], 1);
            atomicAdd(&hist[d.w >> 8], 1);
        }
    }
    __syncthreads();
    for (int i = threadIdx.x; i < nbk; i += 256) blkcnt[(size_t)i * GA + g] = hist[i];
}

// ---- Pass B: two-level exclusive scan over flat blkcnt (F = nbk*GA) ----
__global__ void k_scan_block(const int* __restrict__ in, int* __restrict__ tmp,
                             int* __restrict__ bsum, int F) {
    __shared__ int s[256];
    int i = blockIdx.x * 256 + threadIdx.x;
    int v = (i < F) ? in[i] : 0;
    s[threadIdx.x] = v;
    __syncthreads();
#pragma unroll
    for (int off = 1; off < 256; off <<= 1) {
        int t = (threadIdx.x >= off) ? s[threadIdx.x - off] : 0;
        __syncthreads();
        s[threadIdx.x] += t;
        __syncthreads();
    }
    tmp[i] = s[threadIdx.x] - v;
    if (threadIdx.x == 255) bsum[blockIdx.x] = s[255];
}

__global__ void k_scan_bsums1024(int* __restrict__ bsum, int nb) {
    __shared__ int s[1024];
    int t = threadIdx.x;
    s[t] = (t < nb) ? bsum[t] : 0;
    __syncthreads();
#pragma unroll
    for (int off = 1; off < 1024; off <<= 1) {
        int v = (t >= off) ? s[t - off] : 0;
        __syncthreads();
        s[t] += v;
        __syncthreads();
    }
    if (t < nb) bsum[t] = (t == 0) ? 0 : s[t - 1];
}

__global__ void k_scan_fin(const int* __restrict__ tmp, const int* __restrict__ bsum,
                           int* __restrict__ excl, int F, int E) {
    int i = blockIdx.x * blockDim.x + threadIdx.x;
    if (i > F) return;
    excl[i] = (i < F) ? (tmp[i] + bsum[i >> 8]) : E;
}

// ---- Pass C: partition edges into bucket windows (LDS cursors; PLAIN stores:
//      R16 nt-stores regressed 46us - L2 write-absorption is load-bearing here) ----
__global__ void __launch_bounds__(256)
k_part(const int* __restrict__ ei, int E4, int GA, int nbk,
       const int* __restrict__ excl, int* __restrict__ partbuf) {
    __shared__ int cur[512];
    int g = blockIdx.x;
    for (int i = threadIdx.x; i < nbk; i += 256) cur[i] = excl[(size_t)i * GA + g];
    __syncthreads();
    const iv4* s4 = (const iv4*)ei;
    const iv4* d4 = s4 + E4;
    int base = g * 2048 + threadIdx.x;
#pragma unroll
    for (int k = 0; k < 8; ++k) {
        int idx = base + k * 256;
        if (idx < E4) {
            iv4 d = __builtin_nontemporal_load(d4 + idx);
            iv4 s = __builtin_nontemporal_load(s4 + idx);
            int dd[4] = {d.x, d.y, d.z, d.w};
            int ss[4] = {s.x, s.y, s.z, s.w};
#pragma unroll
            for (int u = 0; u < 4; ++u) {
                int pos = atomicAdd(&cur[dd[u] >> 8], 1);
                partbuf[pos] = (ss[u] << 8) | (dd[u] & 255);
            }
        }
    }
}

// ---- Pass D: per-bucket CSR (LDS node hist + scan; self-loop = slot 0) ----
__global__ void __launch_bounds__(256)
k_csr(const int* __restrict__ excl, const int* __restrict__ partbuf,
      int* __restrict__ ptr, int* __restrict__ srcs, int N, int GA, int nbk, int Et) {
    __shared__ int lcnt[256];
    __shared__ int lsc[256];
    int b = blockIdx.x;
    int tid = threadIdx.x;
    int pStart = excl[(size_t)b * GA];
    int pEnd   = excl[(size_t)(b + 1) * GA];   // b==nbk-1 -> excl[F] = E
    int node = (b << 8) + tid;
    int exists = (node < N) ? 1 : 0;
    lcnt[tid] = exists;                        // slot 0 reserved for self-loop
    __syncthreads();
    for (int i = pStart + tid; i < pEnd; i += 256)
        atomicAdd(&lcnt[partbuf[i] & 255], 1);
    __syncthreads();
    int v = lcnt[tid];
    lsc[tid] = v;
    __syncthreads();
#pragma unroll
    for (int off = 1; off < 256; off <<= 1) {
        int t = (tid >= off) ? lsc[tid - off] : 0;
        __syncthreads();
        lsc[tid] += t;
        __syncthreads();
    }
    int exclv = lsc[tid] - v;
    int finalBase = pStart + (b << 8);         // + self-loops of earlier buckets
    if (exists) {
        int p = finalBase + exclv;
        ptr[node] = p;
        srcs[p] = node;                        // self-loop at rank 0
    }
    if (b == nbk - 1 && tid == 0) ptr[N] = Et;
    __syncthreads();
    lcnt[tid] = exclv + exists;                // cursor: next free slot after self-loop
    __syncthreads();
    for (int i = pStart + tid; i < pEnd; i += 256) {
        int pv = partbuf[i];
        int r = atomicAdd(&lcnt[pv & 255], 1);
        srcs[finalBase + r] = pv >> 8;
    }
}

// ---------------- layer 1: wave per node, a_s recomputed from gathered row ----------------
// Lane (j = l>>3, h = l&7). Per group the ONLY gathers are srcs (32B coalesced)
// and hv (one dwordx4 = head h's channels of row s_j). a_s[s,h] = dot(hv, att_src[h])
// on the fly (4 pk_fma + add) - kills the second random gather + its dependency.

__device__ __forceinline__ float lrelu(float e) { return e > 0.0f ? e : NEG * e; }

__device__ __forceinline__ void proc_group(const iv4& hv, float ad, const fv2* __restrict__ sAsh,
                                           fv2* acc2, float& den, bool valid) {
    unsigned int dw[4] = {(unsigned int)hv.x, (unsigned int)hv.y,
                          (unsigned int)hv.z, (unsigned int)hv.w};
    fv2 g[4];
#pragma unroll
    for (int k = 0; k < 4; ++k)
        g[k] = (fv2){__uint_as_float(dw[k] << 16),
                     __uint_as_float(dw[k] & 0xffff0000u)};
    fv2 d2 = g[0] * sAsh[0];
    d2 += g[1] * sAsh[1];
    d2 += g[2] * sAsh[2];
    d2 += g[3] * sAsh[3];
    float as = d2.x + d2.y;
    float ex = exp2f(fmaf(lrelu(as + ad), LOG2E, SHBIAS));
    if (!valid) ex = 0.0f;
    den += ex;
    fv2 ev = {ex, ex};
#pragma unroll
    for (int k = 0; k < 4; ++k) acc2[k] += ev * g[k];
}

__global__ void __launch_bounds__(256)
k_gat1(const int* __restrict__ ptr, const int* __restrict__ srcs,
       const float* __restrict__ as1, const float* __restrict__ a_d,
       const ushort_t* __restrict__ h1b,
       const float* __restrict__ b1, const float* __restrict__ W2,
       const float* __restrict__ as2, const float* __restrict__ ad2,
       float4* __restrict__ p2, int N) {
    __shared__ float sB1[D1];
    __shared__ float sW2[D1 * 2];
    __shared__ fv2 sAs[D1 / 2];    // att_src1, fv2-paired: sAs[h*4+k] = as1[h*8+2k..2k+1]
    __shared__ float sA2[4];
    if (threadIdx.x < D1) sB1[threadIdx.x] = b1[threadIdx.x];
    else if (threadIdx.x < D1 * 3) sW2[threadIdx.x - D1] = W2[threadIdx.x - D1];
    else if (threadIdx.x < D1 * 4) ((float*)sAs)[threadIdx.x - D1 * 3] = as1[threadIdx.x - D1 * 3];
    if (threadIdx.x < 2) sA2[threadIdx.x] = as2[threadIdx.x];
    else if (threadIdx.x < 4) sA2[threadIdx.x] = ad2[threadIdx.x - 2];
    __syncthreads();
    int n = (blockIdx.x * blockDim.x + threadIdx.x) >> 6;
    if (n >= N) return;
    int l = threadIdx.x & 63;
    int j = l >> 3;          // edge slot
    int h = l & 7;           // head
    int start = ptr[n], end = ptr[n + 1];
    float ad = a_d[n * NH + h];
    const fv2* sAsh = sAs + (h << 2);
    float den = 0.0f;
    fv2 acc2[4];
#pragma unroll
    for (int k = 0; k < 4; ++k) acc2[k] = (fv2){0.0f, 0.0f};
    int base = start;
    // 32-edge maskless main: 4 groups, 8 independent gathers in flight
    for (; base + 32 <= end; base += 32) {
        int i0 = base + j;
        int s0 = srcs[i0], s1 = srcs[i0 + 8], s2 = srcs[i0 + 16], s3 = srcs[i0 + 24];
        iv4 hv0 = *(const iv4*)(h1b + ((size_t)s0 << 6) + (h << 3));
        iv4 hv1 = *(const iv4*)(h1b + ((size_t)s1 << 6) + (h << 3));
        iv4 hv2 = *(const iv4*)(h1b + ((size_t)s2 << 6) + (h << 3));
        iv4 hv3 = *(const iv4*)(h1b + ((size_t)s3 << 6) + (h << 3));
        proc_group(hv0, ad, sAsh, acc2, den, true);
        proc_group(hv1, ad, sAsh, acc2, den, true);
        proc_group(hv2, ad, sAsh, acc2, den, true);
        proc_group(hv3, ad, sAsh, acc2, den, true);
    }
    // maskless 8-edge groups
    for (; base + 8 <= end; base += 8) {
        int s = srcs[base + j];
        iv4 hv = *(const iv4*)(h1b + ((size_t)s << 6) + (h << 3));
        proc_group(hv, ad, sAsh, acc2, den, true);
    }
    // single masked group (<8 edges)
    if (base < end) {
        int idxl = base + j;
        bool valid = idxl < end;
        if (!valid) idxl = end - 1;
        int s = srcs[idxl];
        iv4 hv = *(const iv4*)(h1b + ((size_t)s << 6) + (h << 3));
        proc_group(hv, ad, sAsh, acc2, den, valid);
    }
    // reduce over j (lane bits 3..5)
    den += __shfl_xor(den, 8, 64);
    den += __shfl_xor(den, 16, 64);
    den += __shfl_xor(den, 32, 64);
    float acc[8];
#pragma unroll
    for (int k = 0; k < 4; ++k) { acc[2 * k] = acc2[k].x; acc[2 * k + 1] = acc2[k].y; }
#pragma unroll
    for (int c = 0; c < 8; ++c) {
        acc[c] += __shfl_xor(acc[c], 8, 64);
        acc[c] += __shfl_xor(acc[c], 16, 64);
        acc[c] += __shfl_xor(acc[c], 32, 64);
    }
    float inv = 1.0f / den;
    float r0 = 0.0f, r1 = 0.0f;
#pragma unroll
    for (int c = 0; c < 8; ++c) {
        int col = (h << 3) + c;
        float v = fmaf(acc[c], inv, sB1[col]);
        v = v > 0.0f ? v : expm1f(v);    // ELU
        r0 = fmaf(v, sW2[col * 2 + 0], r0);
        r1 = fmaf(v, sW2[col * 2 + 1], r1);
    }
    // sum over h (lane bits 0..2)
    r0 += __shfl_xor(r0, 1, 64); r0 += __shfl_xor(r0, 2, 64); r0 += __shfl_xor(r0, 4, 64);
    r1 += __shfl_xor(r1, 1, 64); r1 += __shfl_xor(r1, 2, 64); r1 += __shfl_xor(r1, 4, 64);
    if (l == 0) {
        // packed node record for layer 2: (a_s2, a_d2, h2_0, h2_1)
        p2[n] = make_float4(r0 * sA2[0] + r1 * sA2[1],
                            r0 * sA2[2] + r1 * sA2[3], r0, r1);
    }
}

// ---------------- layer 2: 16 lanes per node, single 16B gather ----------------

__global__ void k_gat2(const int* __restrict__ ptr, const int* __restrict__ srcs,
                       const float4* __restrict__ p2, const float* __restrict__ b2,
                       float* __restrict__ out, int N) {
    int t = blockIdx.x * blockDim.x + threadIdx.x;
    int n = t >> 4;
    if (n >= N) return;
    int l = threadIdx.x & 15;
    int start = ptr[n], end = ptr[n + 1];
    float ad = p2[n].y;
    float den = 0.0f, a0 = 0.0f, a1 = 0.0f;
    for (int idx = start + l; idx < end; idx += 16) {
        int s = srcs[idx];
        float4 ps = p2[s];
        float ex = exp2f(fmaf(lrelu(ps.x + ad), LOG2E, SHBIAS));
        den += ex;
        a0 = fmaf(ex, ps.z, a0);
        a1 = fmaf(ex, ps.w, a1);
    }
#pragma unroll
    for (int off = 8; off; off >>= 1) {
        den += __shfl_xor(den, off, 16);
        a0  += __shfl_xor(a0, off, 16);
        a1  += __shfl_xor(a1, off, 16);
    }
    if (l == 0) {
        float inv = 1.0f / den;
        float o0 = a0 * inv + b2[0];
        float o1 = a1 * inv + b2[1];
        float mx = fmaxf(o0, o1);
        float lse = mx + logf(__expf(o0 - mx) + __expf(o1 - mx));
        out[n * 2 + 0] = o0 - lse;
        out[n * 2 + 1] = o1 - lse;
    }
}

extern "C" void kernel_launch(void* const* d_in, const int* in_sizes, int n_in,
                              void* d_out, int out_size, void* d_ws, size_t ws_size,
                              hipStream_t stream) {
    const float* x   = (const float*)d_in[0];
    const int*   ei  = (const int*)d_in[1];
    const float* W1  = (const float*)d_in[2];
    const float* as1 = (const float*)d_in[3];
    const float* ad1 = (const float*)d_in[4];
    const float* b1  = (const float*)d_in[5];
    const float* W2  = (const float*)d_in[6];
    const float* as2 = (const float*)d_in[7];
    const float* ad2 = (const float*)d_in[8];
    const float* b2  = (const float*)d_in[9];
    float* out = (float*)d_out;

    const int N  = in_sizes[0] / F_IN;   // 100000
    const int E  = in_sizes[1] / 2;      // 3200000
    const int E4 = E / 4;                // 800000
    const int Et = E + N;
    const int nbk = (N + 255) >> 8;      // 391 buckets
    const int GA  = (E4 + 2047) >> 11;   // 391 edge-chunk blocks (8192 edges each)
    const int F   = nbk * GA;            // 152881 flat scan size
    const int nbScan = (F + 255) >> 8;   // 598 (<=1024)

    char* p = (char*)d_ws;
    ushort_t* h1b = (ushort_t*)p; p += (size_t)N * D1 * 2;   // bf16 h1 (12.8MB, 16B aligned)
    float4* p2  = (float4*)p; p += (size_t)N * 16;           // packed layer-2 node record
    float* a_d1 = (float*)p; p += (size_t)N * NH * 4;
    int* blkcnt = (int*)p;   p += (size_t)F * 4;
    int* tmp    = (int*)p;   p += (size_t)nbScan * 256 * 4;
    int* bsum   = (int*)p;   p += (size_t)nbScan * 4;
    int* excl   = (int*)p;   p += (size_t)(F + 1) * 4;
    int* partbuf= (int*)p;   p += (size_t)E * 4;
    int* ptr    = (int*)p;   p += (size_t)(N + 1) * 4;
    int* srcs   = (int*)p;   p += (size_t)Et * 4;

    const int nN1 = (N * NH + 255) / 256;    // 3125 node1 blocks

    hipLaunchKernelGGL(k_bhist_node1, dim3(GA + nN1), dim3(256), 0, stream,
                       ei, E4, GA, nbk, blkcnt, x, W1, ad1, h1b, a_d1, N);

    hipLaunchKernelGGL(k_scan_block, dim3(nbScan), dim3(256), 0, stream, blkcnt, tmp, bsum, F);
    hipLaunchKernelGGL(k_scan_bsums1024, dim3(1), dim3(1024), 0, stream, bsum, nbScan);
    hipLaunchKernelGGL(k_scan_fin, dim3((F + 256) / 256), dim3(256), 0, stream,
                       tmp, bsum, excl, F, E);

    hipLaunchKernelGGL(k_part, dim3(GA), dim3(256), 0, stream, ei, E4, GA, nbk, excl, partbuf);

    hipLaunchKernelGGL(k_csr, dim3(nbk), dim3(256), 0, stream,
                       excl, partbuf, ptr, srcs, N, GA, nbk, Et);

    hipLaunchKernelGGL(k_gat1, dim3((N + 3) / 4), dim3(256), 0, stream,
                       ptr, srcs, as1, a_d1, h1b, b1, W2, as2, ad2, p2, N);

    hipLaunchKernelGGL(k_gat2, dim3((N * 16 + 255) / 256), dim3(256), 0, stream,
                       ptr, srcs, p2, b2, out, N);
}

// Round 18
// 204.107 us; speedup vs baseline: 1.2224x; 1.0537x over previous
//
#include <hip/hip_runtime.h>
#include <math.h>

#define F_IN 32
#define NH 8
#define C1 8
#define D1 64
#define NEG 0.2f
#define LOG2E 1.44269504088896f
#define SHBIAS (-20.0f * LOG2E)   // fixed softmax shift (shift-invariant, avoids overflow)

typedef int iv4 __attribute__((ext_vector_type(4)));
typedef float fv2 __attribute__((ext_vector_type(2)));
typedef unsigned short ushort_t;

__device__ __forceinline__ ushort_t f2bf(float f) {   // RNE float->bf16
    unsigned int b = __float_as_uint(f);
    return (ushort_t)((b + 0x7FFF + ((b >> 16) & 1)) >> 16);
}

// =============== CSR build: two-level counting sort, ZERO global atomics ===============
// (R10-R12: ANY per-edge global atomic caps at ~22G/s = 143us on the memory-side
//  coherence point, regardless of layout. So: LDS atomics only.)

// ---- node1: h = x@W1 (stored bf16), attention logits a_s/a_d (f32) ----
__device__ __forceinline__ void node1_body(const float* __restrict__ x, const float* __restrict__ W1,
                                           const float* __restrict__ as1, const float* __restrict__ ad1,
                                           ushort_t* __restrict__ h1b, float* __restrict__ a_s,
                                           float* __restrict__ a_d, int N, int b) {
    __shared__ float sW[F_IN * D1];
    __shared__ float sA[2 * D1];
    for (int i = threadIdx.x; i < F_IN * D1; i += blockDim.x) sW[i] = W1[i];
    if (threadIdx.x < 2 * D1)
        sA[threadIdx.x] = (threadIdx.x < D1) ? as1[threadIdx.x] : ad1[threadIdx.x - D1];
    __syncthreads();
    int t = b * blockDim.x + threadIdx.x;
    int n = t >> 3, h = t & 7;
    if (n >= N) return;
    float xr[F_IN];
    const float4* xv = (const float4*)(x + n * F_IN);
#pragma unroll
    for (int k = 0; k < F_IN / 4; ++k) {
        float4 v = xv[k];
        xr[4 * k] = v.x; xr[4 * k + 1] = v.y; xr[4 * k + 2] = v.z; xr[4 * k + 3] = v.w;
    }
    float acc[C1];
#pragma unroll
    for (int c = 0; c < C1; ++c) acc[c] = 0.0f;
#pragma unroll
    for (int k = 0; k < F_IN; ++k) {
        float xk = xr[k];
#pragma unroll
        for (int c = 0; c < C1; ++c) acc[c] = fmaf(xk, sW[k * D1 + h * C1 + c], acc[c]);
    }
    float s_ = 0.0f, d_ = 0.0f;
    unsigned int w[4];
#pragma unroll
    for (int c = 0; c < C1; ++c) {
        s_ = fmaf(acc[c], sA[h * C1 + c], s_);
        d_ = fmaf(acc[c], sA[D1 + h * C1 + c], d_);
    }
#pragma unroll
    for (int k = 0; k < 4; ++k)
        w[k] = (unsigned int)f2bf(acc[2 * k]) | ((unsigned int)f2bf(acc[2 * k + 1]) << 16);
    iv4 wv = {(int)w[0], (int)w[1], (int)w[2], (int)w[3]};
    *(iv4*)(h1b + (size_t)n * D1 + h * C1) = wv;
    a_s[n * NH + h] = s_;
    a_d[n * NH + h] = d_;
}

// ---- Pass A (|| node1): per-block bucket histogram, 8192 edges/block ----
__global__ void __launch_bounds__(256)
k_bhist_node1(const int* __restrict__ ei, int E4, int GA, int nbk,
              int* __restrict__ blkcnt,
              const float* __restrict__ x, const float* __restrict__ W1,
              const float* __restrict__ as1, const float* __restrict__ ad1,
              ushort_t* __restrict__ h1b, float* __restrict__ a_s, float* __restrict__ a_d,
              int N) {
    int g = blockIdx.x;
    if (g >= GA) { node1_body(x, W1, as1, ad1, h1b, a_s, a_d, N, g - GA); return; }
    __shared__ int hist[512];
    for (int i = threadIdx.x; i < nbk; i += 256) hist[i] = 0;
    __syncthreads();
    const iv4* d4 = (const iv4*)ei + E4;
    int base = g * 2048 + threadIdx.x;
#pragma unroll
    for (int k = 0; k < 8; ++k) {
        int idx = base + k * 256;
        if (idx < E4) {
            iv4 d = __builtin_nontemporal_load(d4 + idx);
            atomicAdd(&hist[d.x >> 8], 1);
            atomicAdd(&hist[d.y >> 8], 1);
            atomicAdd(&hist[d.z >> 8], 1);
            atomicAdd(&hist[d.w >> 8], 1);
        }
    }
    __syncthreads();
    for (int i = threadIdx.x; i < nbk; i += 256) blkcnt[(size_t)i * GA + g] = hist[i];
}

// ---- Pass B: two-level exclusive scan over flat blkcnt (F = nbk*GA) ----
__global__ void k_scan_block(const int* __restrict__ in, int* __restrict__ tmp,
                             int* __restrict__ bsum, int F) {
    __shared__ int s[256];
    int i = blockIdx.x * 256 + threadIdx.x;
    int v = (i < F) ? in[i] : 0;
    s[threadIdx.x] = v;
    __syncthreads();
#pragma unroll
    for (int off = 1; off < 256; off <<= 1) {
        int t = (threadIdx.x >= off) ? s[threadIdx.x - off] : 0;
        __syncthreads();
        s[threadIdx.x] += t;
        __syncthreads();
    }
    tmp[i] = s[threadIdx.x] - v;
    if (threadIdx.x == 255) bsum[blockIdx.x] = s[255];
}

__global__ void k_scan_bsums1024(int* __restrict__ bsum, int nb) {
    __shared__ int s[1024];
    int t = threadIdx.x;
    s[t] = (t < nb) ? bsum[t] : 0;
    __syncthreads();
#pragma unroll
    for (int off = 1; off < 1024; off <<= 1) {
        int v = (t >= off) ? s[t - off] : 0;
        __syncthreads();
        s[t] += v;
        __syncthreads();
    }
    if (t < nb) bsum[t] = (t == 0) ? 0 : s[t - 1];
}

__global__ void k_scan_fin(const int* __restrict__ tmp, const int* __restrict__ bsum,
                           int* __restrict__ excl, int F, int E) {
    int i = blockIdx.x * blockDim.x + threadIdx.x;
    if (i > F) return;
    excl[i] = (i < F) ? (tmp[i] + bsum[i >> 8]) : E;
}

// ---- Pass C: partition edges into bucket windows (LDS cursors; PLAIN stores:
//      R16 nt-stores regressed 46us - L2 write-absorption is load-bearing here) ----
__global__ void __launch_bounds__(256)
k_part(const int* __restrict__ ei, int E4, int GA, int nbk,
       const int* __restrict__ excl, int* __restrict__ partbuf) {
    __shared__ int cur[512];
    int g = blockIdx.x;
    for (int i = threadIdx.x; i < nbk; i += 256) cur[i] = excl[(size_t)i * GA + g];
    __syncthreads();
    const iv4* s4 = (const iv4*)ei;
    const iv4* d4 = s4 + E4;
    int base = g * 2048 + threadIdx.x;
#pragma unroll
    for (int k = 0; k < 8; ++k) {
        int idx = base + k * 256;
        if (idx < E4) {
            iv4 d = __builtin_nontemporal_load(d4 + idx);
            iv4 s = __builtin_nontemporal_load(s4 + idx);
            int dd[4] = {d.x, d.y, d.z, d.w};
            int ss[4] = {s.x, s.y, s.z, s.w};
#pragma unroll
            for (int u = 0; u < 4; ++u) {
                int pos = atomicAdd(&cur[dd[u] >> 8], 1);
                partbuf[pos] = (ss[u] << 8) | (dd[u] & 255);
            }
        }
    }
}

// ---- Pass D: per-bucket CSR (LDS node hist + scan; self-loop = slot 0) ----
__global__ void __launch_bounds__(256)
k_csr(const int* __restrict__ excl, const int* __restrict__ partbuf,
      int* __restrict__ ptr, int* __restrict__ srcs, int N, int GA, int nbk, int Et) {
    __shared__ int lcnt[256];
    __shared__ int lsc[256];
    int b = blockIdx.x;
    int tid = threadIdx.x;
    int pStart = excl[(size_t)b * GA];
    int pEnd   = excl[(size_t)(b + 1) * GA];   // b==nbk-1 -> excl[F] = E
    int node = (b << 8) + tid;
    int exists = (node < N) ? 1 : 0;
    lcnt[tid] = exists;                        // slot 0 reserved for self-loop
    __syncthreads();
    for (int i = pStart + tid; i < pEnd; i += 256)
        atomicAdd(&lcnt[partbuf[i] & 255], 1);
    __syncthreads();
    int v = lcnt[tid];
    lsc[tid] = v;
    __syncthreads();
#pragma unroll
    for (int off = 1; off < 256; off <<= 1) {
        int t = (tid >= off) ? lsc[tid - off] : 0;
        __syncthreads();
        lsc[tid] += t;
        __syncthreads();
    }
    int exclv = lsc[tid] - v;
    int finalBase = pStart + (b << 8);         // + self-loops of earlier buckets
    if (exists) {
        int p = finalBase + exclv;
        ptr[node] = p;
        srcs[p] = node;                        // self-loop at rank 0
    }
    if (b == nbk - 1 && tid == 0) ptr[N] = Et;
    __syncthreads();
    lcnt[tid] = exclv + exists;                // cursor: next free slot after self-loop
    __syncthreads();
    for (int i = pStart + tid; i < pEnd; i += 256) {
        int pv = partbuf[i];
        int r = atomicAdd(&lcnt[pv & 255], 1);
        srcs[finalBase + r] = pv >> 8;
    }
}

// ---------------- layer 1: wave per node, vectorized row gather + pk_fma ----------------
// Lane (j = l>>3, h = l&7). Main loop is maskless (base+16<=end), 2 edge-groups
// in flight (4 gathers), float2 accumulators -> v_pk_fma_f32. EXACT unpack
// (R16's free-hi-unpack doubled absmax for zero perf). This config is at the
// measured random-gather ceiling: 277MB @ ~3.05 TB/s = 93us, VALU ~90% (balanced).

__device__ __forceinline__ float lrelu(float e) { return e > 0.0f ? e : NEG * e; }

__global__ void __launch_bounds__(256)
k_gat1(const int* __restrict__ ptr, const int* __restrict__ srcs,
       const float* __restrict__ a_s, const float* __restrict__ a_d,
       const ushort_t* __restrict__ h1b,
       const float* __restrict__ b1, const float* __restrict__ W2,
       const float* __restrict__ as2, const float* __restrict__ ad2,
       float4* __restrict__ p2, int N) {
    __shared__ float sB1[D1];
    __shared__ float sW2[D1 * 2];
    __shared__ float sA2[4];
    if (threadIdx.x < D1) sB1[threadIdx.x] = b1[threadIdx.x];
    else if (threadIdx.x < D1 * 3) sW2[threadIdx.x - D1] = W2[threadIdx.x - D1];
    else if (threadIdx.x < D1 * 3 + 2) sA2[threadIdx.x - D1 * 3] = as2[threadIdx.x - D1 * 3];
    else if (threadIdx.x < D1 * 3 + 4) sA2[threadIdx.x - D1 * 3] = ad2[threadIdx.x - D1 * 3 - 2];
    __syncthreads();
    int n = (blockIdx.x * blockDim.x + threadIdx.x) >> 6;
    if (n >= N) return;
    int l = threadIdx.x & 63;
    int j = l >> 3;          // edge slot
    int h = l & 7;           // head
    int start = ptr[n], end = ptr[n + 1];
    float ad = a_d[n * NH + h];
    float den = 0.0f;
    fv2 acc2[4];
#pragma unroll
    for (int k = 0; k < 4; ++k) acc2[k] = (fv2){0.0f, 0.0f};
    int base = start;
    // maskless main loop: 16 edges/iter, 2 groups pipelined
    for (; base + 16 <= end; base += 16) {
        int i0 = base + j;
        int s0 = srcs[i0], s1 = srcs[i0 + 8];
        float as0 = a_s[(s0 << 3) + h], as1 = a_s[(s1 << 3) + h];
        iv4 hv0 = *(const iv4*)(h1b + ((size_t)s0 << 6) + (h << 3));
        iv4 hv1 = *(const iv4*)(h1b + ((size_t)s1 << 6) + (h << 3));
        float ex0 = exp2f(fmaf(lrelu(as0 + ad), LOG2E, SHBIAS));
        float ex1 = exp2f(fmaf(lrelu(as1 + ad), LOG2E, SHBIAS));
        den += ex0 + ex1;
        fv2 e0 = {ex0, ex0}, e1 = {ex1, ex1};
        int dw0[4] = {hv0.x, hv0.y, hv0.z, hv0.w};
        int dw1[4] = {hv1.x, hv1.y, hv1.z, hv1.w};
#pragma unroll
        for (int k = 0; k < 4; ++k) {
            fv2 g0 = {__uint_as_float(((unsigned int)dw0[k]) << 16),
                      __uint_as_float(((unsigned int)dw0[k]) & 0xffff0000u)};
            fv2 g1 = {__uint_as_float(((unsigned int)dw1[k]) << 16),
                      __uint_as_float(((unsigned int)dw1[k]) & 0xffff0000u)};
            acc2[k] += e0 * g0;      // v_pk_fma_f32
            acc2[k] += e1 * g1;
        }
    }
    // masked tail (<=15 edges)
    for (; base < end; base += 8) {
        int idxl = base + j;
        bool valid = idxl < end;
        if (!valid) idxl = end - 1;
        int s = srcs[idxl];
        float as = a_s[(s << 3) + h];
        float ex = exp2f(fmaf(lrelu(as + ad), LOG2E, SHBIAS));
        if (!valid) ex = 0.0f;
        den += ex;
        iv4 hv = *(const iv4*)(h1b + ((size_t)s << 6) + (h << 3));
        int dw[4] = {hv.x, hv.y, hv.z, hv.w};
        fv2 ev = {ex, ex};
#pragma unroll
        for (int k = 0; k < 4; ++k) {
            fv2 g = {__uint_as_float(((unsigned int)dw[k]) << 16),
                     __uint_as_float(((unsigned int)dw[k]) & 0xffff0000u)};
            acc2[k] += ev * g;
        }
    }
    // reduce over j (lane bits 3..5)
    den += __shfl_xor(den, 8, 64);
    den += __shfl_xor(den, 16, 64);
    den += __shfl_xor(den, 32, 64);
    float acc[8];
#pragma unroll
    for (int k = 0; k < 4; ++k) { acc[2 * k] = acc2[k].x; acc[2 * k + 1] = acc2[k].y; }
#pragma unroll
    for (int c = 0; c < 8; ++c) {
        acc[c] += __shfl_xor(acc[c], 8, 64);
        acc[c] += __shfl_xor(acc[c], 16, 64);
        acc[c] += __shfl_xor(acc[c], 32, 64);
    }
    float inv = 1.0f / den;
    float r0 = 0.0f, r1 = 0.0f;
#pragma unroll
    for (int c = 0; c < 8; ++c) {
        int col = (h << 3) + c;
        float v = fmaf(acc[c], inv, sB1[col]);
        v = v > 0.0f ? v : expm1f(v);    // ELU
        r0 = fmaf(v, sW2[col * 2 + 0], r0);
        r1 = fmaf(v, sW2[col * 2 + 1], r1);
    }
    // sum over h (lane bits 0..2)
    r0 += __shfl_xor(r0, 1, 64); r0 += __shfl_xor(r0, 2, 64); r0 += __shfl_xor(r0, 4, 64);
    r1 += __shfl_xor(r1, 1, 64); r1 += __shfl_xor(r1, 2, 64); r1 += __shfl_xor(r1, 4, 64);
    if (l == 0) {
        // packed node record for layer 2: (a_s2, a_d2, h2_0, h2_1)
        p2[n] = make_float4(r0 * sA2[0] + r1 * sA2[1],
                            r0 * sA2[2] + r1 * sA2[3], r0, r1);
    }
}

// ---------------- layer 2: 16 lanes per node, single 16B gather ----------------

__global__ void k_gat2(const int* __restrict__ ptr, const int* __restrict__ srcs,
                       const float4* __restrict__ p2, const float* __restrict__ b2,
                       float* __restrict__ out, int N) {
    int t = blockIdx.x * blockDim.x + threadIdx.x;
    int n = t >> 4;
    if (n >= N) return;
    int l = threadIdx.x & 15;
    int start = ptr[n], end = ptr[n + 1];
    float ad = p2[n].y;
    float den = 0.0f, a0 = 0.0f, a1 = 0.0f;
    for (int idx = start + l; idx < end; idx += 16) {
        int s = srcs[idx];
        float4 ps = p2[s];
        float ex = exp2f(fmaf(lrelu(ps.x + ad), LOG2E, SHBIAS));
        den += ex;
        a0 = fmaf(ex, ps.z, a0);
        a1 = fmaf(ex, ps.w, a1);
    }
#pragma unroll
    for (int off = 8; off; off >>= 1) {
        den += __shfl_xor(den, off, 16);
        a0  += __shfl_xor(a0, off, 16);
        a1  += __shfl_xor(a1, off, 16);
    }
    if (l == 0) {
        float inv = 1.0f / den;
        float o0 = a0 * inv + b2[0];
        float o1 = a1 * inv + b2[1];
        float mx = fmaxf(o0, o1);
        float lse = mx + logf(__expf(o0 - mx) + __expf(o1 - mx));
        out[n * 2 + 0] = o0 - lse;
        out[n * 2 + 1] = o1 - lse;
    }
}

extern "C" void kernel_launch(void* const* d_in, const int* in_sizes, int n_in,
                              void* d_out, int out_size, void* d_ws, size_t ws_size,
                              hipStream_t stream) {
    const float* x   = (const float*)d_in[0];
    const int*   ei  = (const int*)d_in[1];
    const float* W1  = (const float*)d_in[2];
    const float* as1 = (const float*)d_in[3];
    const float* ad1 = (const float*)d_in[4];
    const float* b1  = (const float*)d_in[5];
    const float* W2  = (const float*)d_in[6];
    const float* as2 = (const float*)d_in[7];
    const float* ad2 = (const float*)d_in[8];
    const float* b2  = (const float*)d_in[9];
    float* out = (float*)d_out;

    const int N  = in_sizes[0] / F_IN;   // 100000
    const int E  = in_sizes[1] / 2;      // 3200000
    const int E4 = E / 4;                // 800000
    const int Et = E + N;
    const int nbk = (N + 255) >> 8;      // 391 buckets
    const int GA  = (E4 + 2047) >> 11;   // 391 edge-chunk blocks (8192 edges each)
    const int F   = nbk * GA;            // 152881 flat scan size
    const int nbScan = (F + 255) >> 8;   // 598 (<=1024)

    char* p = (char*)d_ws;
    ushort_t* h1b = (ushort_t*)p; p += (size_t)N * D1 * 2;   // bf16 h1 (12.8MB, 16B aligned)
    float4* p2  = (float4*)p; p += (size_t)N * 16;           // packed layer-2 node record
    float* a_s1 = (float*)p; p += (size_t)N * NH * 4;
    float* a_d1 = (float*)p; p += (size_t)N * NH * 4;
    int* blkcnt = (int*)p;   p += (size_t)F * 4;
    int* tmp    = (int*)p;   p += (size_t)nbScan * 256 * 4;
    int* bsum   = (int*)p;   p += (size_t)nbScan * 4;
    int* excl   = (int*)p;   p += (size_t)(F + 1) * 4;
    int* partbuf= (int*)p;   p += (size_t)E * 4;
    int* ptr    = (int*)p;   p += (size_t)(N + 1) * 4;
    int* srcs   = (int*)p;   p += (size_t)Et * 4;

    const int nN1 = (N * NH + 255) / 256;    // 3125 node1 blocks

    hipLaunchKernelGGL(k_bhist_node1, dim3(GA + nN1), dim3(256), 0, stream,
                       ei, E4, GA, nbk, blkcnt, x, W1, as1, ad1, h1b, a_s1, a_d1, N);

    hipLaunchKernelGGL(k_scan_block, dim3(nbScan), dim3(256), 0, stream, blkcnt, tmp, bsum, F);
    hipLaunchKernelGGL(k_scan_bsums1024, dim3(1), dim3(1024), 0, stream, bsum, nbScan);
    hipLaunchKernelGGL(k_scan_fin, dim3((F + 256) / 256), dim3(256), 0, stream,
                       tmp, bsum, excl, F, E);

    hipLaunchKernelGGL(k_part, dim3(GA), dim3(256), 0, stream, ei, E4, GA, nbk, excl, partbuf);

    hipLaunchKernelGGL(k_csr, dim3(nbk), dim3(256), 0, stream,
                       excl, partbuf, ptr, srcs, N, GA, nbk, Et);

    hipLaunchKernelGGL(k_gat1, dim3((N + 3) / 4), dim3(256), 0, stream,
                       ptr, srcs, a_s1, a_d1, h1b, b1, W2, as2, ad2, p2, N);

    hipLaunchKernelGGL(k_gat2, dim3((N * 16 + 255) / 256), dim3(256), 0, stream,
                       ptr, srcs, p2, b2, out, N);
}